// Round 2
// baseline (458.903 us; speedup 1.0000x reference)
//
#include <hip/hip_runtime.h>

// B=4096, N=F=16384. out[b,n] = relu(enc[b,pref[n]]*w[n] - 0.1*mean_b)
// Key identity: mean_b = (1/N) * sum_f enc[b,f] * c[f],  c[f] = sum_{pref[n]&(F-1)==f} w[n]
// -> mean computed as a streaming dot during LDS staging; no gathered values
//    need to live in registers across the reduction (R1 kernel spilled v[32]).

constexpr int B_ROWS  = 4096;
constexpr int N_NEUR  = 16384;
constexpr int F_FEAT  = 16384;
constexpr float MEAN_SUB = 0.1f;

constexpr int T_MAIN = 1024;               // 16 waves/block, 2 blocks/CU (LDS-capped)
constexpr int ITER4  = F_FEAT / 4 / T_MAIN; // 4 float4 iters per phase

// ---- pre-kernel: build c[f] in ws via LDS scatter-add (single block) ----
__global__ void __launch_bounds__(1024)
build_c_kernel(const float* __restrict__ w, const int* __restrict__ pref,
               float* __restrict__ c_out) {
    __shared__ float c[F_FEAT];
    const int tid = threadIdx.x;
    float4* c4 = (float4*)c;
    #pragma unroll
    for (int j = 0; j < F_FEAT / 4 / 1024; ++j)
        c4[tid + j * 1024] = make_float4(0.f, 0.f, 0.f, 0.f);
    __syncthreads();
    #pragma unroll
    for (int j = 0; j < N_NEUR / 1024; ++j) {
        const int n = tid + j * 1024;
        atomicAdd(&c[pref[n] & (F_FEAT - 1)], w[n]);
    }
    __syncthreads();
    #pragma unroll
    for (int j = 0; j < F_FEAT / 4 / 1024; ++j)
        ((float4*)c_out)[tid + j * 1024] = c4[tid + j * 1024];
}

// ---- main kernel: one block per row ----
__global__ void __launch_bounds__(T_MAIN, 8)
sensory_kernel(const float* __restrict__ enc,
               const float* __restrict__ w,
               const int*   __restrict__ pref,
               const float* __restrict__ c,
               float*       __restrict__ out) {
    __shared__ float row[F_FEAT];          // 64 KB

    const int tid = threadIdx.x;
    const int b   = blockIdx.x;

    // Phase A: stage row -> LDS, streaming dot with c (mean precursor)
    const float4* __restrict__ rowg4 = (const float4*)(enc + (size_t)b * F_FEAT);
    const float4* __restrict__ cg4   = (const float4*)c;
    float4* row4 = (float4*)row;
    float dot = 0.f;
    #pragma unroll
    for (int j = 0; j < ITER4; ++j) {
        const int i = tid + j * T_MAIN;
        const float4 e  = rowg4[i];
        const float4 cc = cg4[i];
        row4[i] = e;
        dot += (e.x * cc.x + e.y * cc.y) + (e.z * cc.z + e.w * cc.w);
    }
    // wave-level reduce
    #pragma unroll
    for (int off = 32; off > 0; off >>= 1)
        dot += __shfl_down(dot, off, 64);

    __syncthreads();                               // staging + dot inputs done
    // borrow row[0..15] for cross-wave reduction; save originals first
    float save = (tid < T_MAIN / 64) ? row[tid] : 0.f;
    __syncthreads();                               // saves complete
    if ((tid & 63) == 0) row[tid >> 6] = dot;      // 16 wave partials
    __syncthreads();                               // partials visible
    float tot = 0.f;
    #pragma unroll
    for (int i = 0; i < T_MAIN / 64; ++i) tot += row[i];
    const float sub = tot * (MEAN_SUB / (float)N_NEUR);
    __syncthreads();                               // everyone read partials
    if (tid < T_MAIN / 64) row[tid] = save;        // restore borrowed slots
    __syncthreads();                               // row fully valid again

    // Phase B: gather from LDS, scale, subtract, relu, coalesced store
    float* __restrict__ outrow = out + (size_t)b * N_NEUR;
    #pragma unroll
    for (int k = 0; k < ITER4; ++k) {
        const int i  = tid + k * T_MAIN;
        const int4   p4 = ((const int4*)pref)[i];
        const float4 w4 = ((const float4*)w)[i];
        float4 o;
        o.x = fmaxf(row[p4.x & (F_FEAT - 1)] * w4.x - sub, 0.f);
        o.y = fmaxf(row[p4.y & (F_FEAT - 1)] * w4.y - sub, 0.f);
        o.z = fmaxf(row[p4.z & (F_FEAT - 1)] * w4.z - sub, 0.f);
        o.w = fmaxf(row[p4.w & (F_FEAT - 1)] * w4.w - sub, 0.f);
        ((float4*)outrow)[i] = o;
    }
}

extern "C" void kernel_launch(void* const* d_in, const int* in_sizes, int n_in,
                              void* d_out, int out_size, void* d_ws, size_t ws_size,
                              hipStream_t stream) {
    const float* enc  = (const float*)d_in[0];   // [B, F] f32
    const float* w    = (const float*)d_in[1];   // [N] f32
    const int*   pref = (const int*)d_in[2];     // [N] i32
    float*       out  = (float*)d_out;           // [B, N] f32
    float*       c    = (float*)d_ws;            // [F] f32 scratch

    build_c_kernel<<<1, 1024, 0, stream>>>(w, pref, c);
    sensory_kernel<<<B_ROWS, T_MAIN, 0, stream>>>(enc, w, pref, c, out);
}